// Round 15
// baseline (876.683 us; speedup 1.0000x reference)
//
#include <hip/hip_runtime.h>
#include <hip/hip_fp16.h>

// LSTM_48850958024796 — R15: gemm_xg fused into lstm_l1 as producer waves.
// lstm_l1 (256 blk, 1024 thr, MB1=4): waves 0..6 = scan (R14-exact cell math);
// waves 7..15 = xg producers: per iter t they MFMA xg(t+2) from an LDS-staged
// h0 double-buffer (B2, parity t&1) into a 3-slot f32 LDS ring (xgr), using
// the idle matrix pipe. Scan waves read xg from the ring (no global xg, no f16
// cvt). Removes the gemm_xg kernel, one launch boundary, and the xg HBM
// round-trip. l0 / pack unchanged from R14.
// Scan math (R3-proven): gates^T = W(A) @ [h|x|1]^T(B), cols gate-interleaved
// (n'=4j+gate). l1 mapping (R14): lane(q,l16), m=l16&3, g16=l16>>2, tile
// myMt=w*4+g16, jme=myMt*4+q; gates spread via 4x ds_swizzle(0x13) + select.

typedef __attribute__((ext_vector_type(8))) short bf16x8;
typedef __attribute__((ext_vector_type(4))) float f32x4;

constexpr int Bsz = 1024, Tt = 128, IN_ = 5, H = 100, G = 400, D1 = 200;
constexpr int NP = 512;   // packed gate cols (32 tiles of 16)
constexpr int NT = 25;    // real tiles (400/16)
constexpr int MB = 8;     // batch rows per block (l0)
constexpr int MB1 = 4;    // batch rows per block (l1)

__device__ __forceinline__ float sigm(float x)   { return 1.f / (1.f + __expf(-x)); }
__device__ __forceinline__ float tanhf_(float x) { return 1.f - 2.f / (__expf(2.f * x) + 1.f); }
__device__ __forceinline__ unsigned short f2bf(float f) {
  unsigned u = __float_as_uint(f);
  u += 0x7fff + ((u >> 16) & 1);
  return (unsigned short)(u >> 16);
}
// src lane = lane & ~8: MB=8 2-way spread (l0)
__device__ __forceinline__ float partner8(float v) {
  return __uint_as_float(
      (unsigned)__builtin_amdgcn_ds_swizzle((int)__float_as_uint(v), 0x17));
}
// src lane = lane & ~12: MB1=4 4-way spread (l1)
__device__ __forceinline__ float partner4(float v) {
  return __uint_as_float(
      (unsigned)__builtin_amdgcn_ds_swizzle((int)__float_as_uint(v), 0x13));
}

// packed col n' (0..511): j=n'>>2, gate=n'&3, src row n = gate*100+j; j>=100->0
__device__ __forceinline__ void pack_body(
    const float* wA, int KA, const float* wB, int KB, int kbo,
    const float* b1, const float* b2, int bias_k,
    unsigned short* dst, int Kg, int idx) {
  if (idx >= Kg * NP * 8) return;
  int jj = idx & 7, rest = idx >> 3;
  int np_ = rest % NP, g = rest / NP;
  int j = np_ >> 2, gate = np_ & 3;
  int k = g * 8 + jj;
  float v = 0.f;
  if (j < H) {
    int n = gate * H + j;
    if (k < KA) v = wA[n * KA + k];
    else if (KB > 0 && k >= kbo && k < kbo + KB) v = wB[n * KB + (k - kbo)];
    else if (k == bias_k) v = b1[n] + b2[n];
  }
  dst[idx] = f2bf(v);
}

__global__ void pack_all(
    const float* __restrict__ w_hh_l0f, const float* __restrict__ w_ih_l0f,
    const float* __restrict__ b_ih_l0f, const float* __restrict__ b_hh_l0f,
    const float* __restrict__ w_hh_l0b, const float* __restrict__ w_ih_l0b,
    const float* __restrict__ b_ih_l0b, const float* __restrict__ b_hh_l0b,
    const float* __restrict__ w_hh_l1f, const float* __restrict__ b_ih_l1f,
    const float* __restrict__ b_hh_l1f,
    const float* __restrict__ w_ih_l1f, const float* __restrict__ w_ih_l1b,
    const float* __restrict__ b_ih_l1b, const float* __restrict__ b_hh_l1b,
    unsigned short* __restrict__ pk0f, unsigned short* __restrict__ pk0b,
    unsigned short* __restrict__ pkhh, unsigned short* __restrict__ pkxg,
    unsigned short* __restrict__ pk1b) {
  int idx = blockIdx.x * 256 + threadIdx.x;
  switch (blockIdx.y) {
    case 0: pack_body(w_hh_l0f, 100, w_ih_l0f, 5, 100, b_ih_l0f, b_hh_l0f, 105, pk0f, 16, idx); break;
    case 1: pack_body(w_hh_l0b, 100, w_ih_l0b, 5, 100, b_ih_l0b, b_hh_l0b, 105, pk0b, 16, idx); break;
    case 2: pack_body(w_hh_l1f, 100, nullptr, 0, 0, b_ih_l1f, b_hh_l1f, -1, pkhh, 16, idx); break;
    case 3: pack_body(w_ih_l1f, 200, nullptr, 0, 0, b_ih_l1f, b_hh_l1f, 200, pkxg, 28, idx); break;
    default: pack_body(w_ih_l1b, 200, nullptr, 0, 0, b_ih_l1b, b_hh_l1b, 200, pk1b, 28, idx);
  }
}

// ------------- layer 0 scan (grid = 128 x 2 dirs, 1024 thr) — R14-exact -----
__global__ __launch_bounds__(1024, 1) void lstm_l0(
    const float* __restrict__ x,
    const unsigned short* __restrict__ pk_f, const unsigned short* __restrict__ pk_b,
    unsigned short* __restrict__ h0fT, unsigned short* __restrict__ h0bT) {
  __shared__ __align__(16) short A_s[2][16][16][8];  // [buf][kg][m16][jj], K=128

  const int tid = threadIdx.x;
  const int lane = tid & 63, w = tid >> 6;       // 16 waves
  const int q = lane >> 4, l16 = lane & 15;
  const int b0 = blockIdx.x * MB;
  const int dir = blockIdx.y;
  const unsigned short* pk = dir ? pk_b : pk_f;
  unsigned short* hT = dir ? h0bT : h0fT;

  for (int i = tid; i < 2 * 16 * 16 * 8; i += 1024) ((short*)A_s)[i] = 0;

  const int mtA = w, mtB = w + 16;
  const bool bvalid = (mtB < NT);
  bf16x8 wfA[4], wfB[4];
#pragma unroll
  for (int kt = 0; kt < 4; ++kt) {
    wfA[kt] = *(const bf16x8*)(pk + ((size_t)(kt * 4 + q) * NP + mtA * 16 + l16) * 8);
    wfB[kt] = *(const bf16x8*)(pk + ((size_t)(kt * 4 + q) * NP + mtB * 16 + l16) * 8);
  }
  float c = 0.f;
  const bool up = (l16 >= 8);
  const int mm = l16 & 7;
  const int j = (up ? mtB : mtA) * 4 + q;
  const bool valid = up ? bvalid : true;
  const int xm = tid / IN_, xe = tid - xm * IN_;              // x loader (tid<40)
  const int sm = tid / 25, sj = (tid - (tid / 25) * 25) * 4;  // h store (tid<200)
  const float* xp = x + ((size_t)(b0 + xm) * Tt + (dir ? Tt - 2 : 1)) * IN_ + xe;
  const int xstride = dir ? -IN_ : IN_;
  unsigned short* hp =
      hT + ((size_t)(dir ? Tt - 1 : 0) * Bsz + b0 + sm) * H + sj;
  const int hstride = dir ? -(Bsz * H) : (Bsz * H);
  __syncthreads();
  if (tid < 16) {  // bias-one col k=105 (kg13,jj1), both bufs
    A_s[0][13][tid][1] = (short)f2bf(1.f);
    A_s[1][13][tid][1] = (short)f2bf(1.f);
  }
  if (tid < MB * IN_) {  // x(t_first) -> buf0, direct f32 read
    int t0 = dir ? (Tt - 1) : 0;
    int k = 100 + xe;
    A_s[0][k >> 3][xm][k & 7] =
        (short)f2bf(x[((size_t)(b0 + xm) * Tt + t0) * IN_ + xe]);
  }
  __syncthreads();

  int p = 0;
  for (int step = 0; step < Tt; ++step) {
    if (step > 0 && tid < 200) {  // coalesced store of h(prev) from buf p
      uint2 hv = *(const uint2*)&A_s[p][sj >> 3][sm][sj & 7];
      *(uint2*)hp = hv;
      hp += hstride;
    }
    float xn = 0.f;
    const bool do_x = (tid < MB * IN_) && (step < Tt - 1);
    if (do_x) { xn = *xp; xp += xstride; }
    bf16x8 hfrag[4];
#pragma unroll
    for (int kt = 0; kt < 4; ++kt) hfrag[kt] = *(const bf16x8*)A_s[p][kt * 4 + q][l16];
    f32x4 accA = (f32x4){0.f, 0.f, 0.f, 0.f};
    f32x4 accB = (f32x4){0.f, 0.f, 0.f, 0.f};
#pragma unroll
    for (int kt = 0; kt < 4; ++kt)
      accA = __builtin_amdgcn_mfma_f32_16x16x32_bf16(wfA[kt], hfrag[kt], accA, 0, 0, 0);
    if (bvalid) {
#pragma unroll
      for (int kt = 0; kt < 4; ++kt)
        accB = __builtin_amdgcn_mfma_f32_16x16x32_bf16(wfB[kt], hfrag[kt], accB, 0, 0, 0);
    }
    float pb0 = partner8(accB[0]), pb1 = partner8(accB[1]);
    float pb2 = partner8(accB[2]), pb3 = partner8(accB[3]);
    float g0 = up ? pb0 : accA[0];
    float g1 = up ? pb1 : accA[1];
    float g2 = up ? pb2 : accA[2];
    float g3 = up ? pb3 : accA[3];
    float cc = sigm(g1) * c + sigm(g0) * tanhf_(g2);
    c = cc;
    float h = sigm(g3) * tanhf_(cc);
    if (valid) A_s[1 - p][j >> 3][mm][j & 7] = (short)f2bf(h);
    if (do_x) {
      int k = 100 + xe;
      A_s[1 - p][k >> 3][xm][k & 7] = (short)f2bf(xn);
    }
    __syncthreads();
    p ^= 1;
  }
  if (tid < 200) *(uint2*)hp = *(const uint2*)&A_s[p][sj >> 3][sm][sj & 7];  // final h
}

// ---- layer 1 fused: scan waves (0..6) + xg producer waves (7..15) ----------
__global__ __launch_bounds__(1024, 1) void lstm_l1(
    const unsigned short* __restrict__ h0fT, const unsigned short* __restrict__ h0bT,
    const unsigned short* __restrict__ pk_hh, const unsigned short* __restrict__ pkxg,
    const unsigned short* __restrict__ pk1b,
    const float* __restrict__ fc_w, const float* __restrict__ fc_b,
    float* __restrict__ out) {
  __shared__ __align__(16) short A_s[2][16][16][8];      // h1, K=128 (m 0..3 used)
  __shared__ __align__(16) short B2_s[2][28][16][8];     // h0 staging, K=224
  __shared__ __align__(16) float xgr[3 * 4 * 100 * 4];   // xg ring [slot][m][j][gate]
  __shared__ __align__(16) short A2_s[28][16][8];        // epilogue [h0|1] K=224
  __shared__ float hf_s[MB1][H];
  __shared__ float hb_s[MB1][H];
  __shared__ float fcw_s[3 * D1];
  __shared__ float fcb_s[3];
  __shared__ float logit_s[MB1][3];

  const int tid = threadIdx.x;
  const int lane = tid & 63, w = tid >> 6;   // 16 waves
  const int q = lane >> 4, l16 = lane & 15;
  const int b0 = blockIdx.x * MB1;           // 256 blocks

  for (int i = tid; i < 2 * 16 * 16 * 8; i += 1024) ((short*)A_s)[i] = 0;
  for (int i = tid; i < 25 * 16 * 8; i += 1024) ((short*)A2_s)[i] = 0;  // kg 0..24
  for (int i = tid; i < 3 * 16 * 8; i += 1024) {  // A2 kg25..27 zero + bias-one
    int jj = i & 7, gl = i >> 7;
    ((short*)&A2_s[25][0][0])[i] = (short)((gl == 0 && jj == 0) ? f2bf(1.f) : 0);
  }
  // B2 kg25..27 both slots: zero + bias-one at k=200 (kg25,jj0)
  for (int i = tid; i < 2 * 3 * 16 * 8; i += 1024) {
    int s = i / 384, off = i - s * 384;
    ((short*)&B2_s[s][25][0][0])[off] =
        (short)((off < 128 && (off & 7) == 0) ? f2bf(1.f) : 0);
  }
  for (int i = tid; i < 3 * D1; i += 1024) fcw_s[i] = fc_w[i];
  if (tid < 3) fcb_s[tid] = fc_b[tid];

  // ---------- role setup ----------
  const bool busy = (w < 7);                 // scan waves: tiles 4w..4w+3
  const int m = l16 & 3, g16 = l16 >> 2;
  const int myMt = w * 4 + g16;
  const int jme = myMt * 4 + q;
  const bool evalid = busy && (myMt < NT);
  int mts[4]; bool tv[4];
  bf16x8 wf[4][4];
  if (busy) {
#pragma unroll
    for (int i = 0; i < 4; ++i) {
      int mt = w * 4 + i; mts[i] = mt; tv[i] = (mt < NT);
#pragma unroll
      for (int kt = 0; kt < 4; ++kt)
        wf[i][kt] = *(const bf16x8*)(pk_hh + ((size_t)(kt * 4 + q) * NP + mt * 16 + l16) * 8);
    }
  }
  float c = 0.f;

  // gemm-producer waves (w>=7): 3 xg tiles each, h0 loader lanes gtid<200
  const int gtid = tid - 448;                // 0..575 for w>=7
  const bool gw = (w >= 7);
  int xti[3]; bool xtv[3];
  bf16x8 wx[3][7];
  if (gw) {
    int g = w - 7;                           // 0..8
#pragma unroll
    for (int i = 0; i < 3; ++i) {
      int ti = g * 3 + i; xti[i] = ti; xtv[i] = (ti < NT);
#pragma unroll
      for (int kt = 0; kt < 7; ++kt)
        wx[i][kt] = *(const bf16x8*)(pkxg + ((size_t)(kt * 4 + q) * NP + ti * 16 + l16) * 8);
    }
  }
  const bool ldr = gw && (gtid < 200);
  const bool lf = (gtid < 100);
  const int lr = lf ? gtid : (gtid - 100);
  const int pm = lr / 25, pj = (lr - pm * 25) * 4;
  const int dstk = lf ? pj : (100 + pj);
  const unsigned short* hsrc = lf ? h0fT : h0bT;
  const unsigned short* ph =
      hsrc + ((size_t)3 * Bsz + b0 + pm) * H + pj;   // running ptr, starts t=3

  // ---------- warm-up: stage h0(0),h0(1); compute xg(0),xg(1); stage h0(2) --
  if (tid < 400) {  // W1: slots 0,1
    int s = tid / 200, r = tid - s * 200;
    bool f2 = (r < 100);
    int r2 = f2 ? r : (r - 100);
    int m2 = r2 / 25, j0 = (r2 - m2 * 25) * 4;
    int k = f2 ? j0 : (100 + j0);
    const unsigned short* src = f2 ? h0fT : h0bT;
    *(uint2*)&B2_s[s][k >> 3][m2][k & 7] =
        *(const uint2*)(src + ((size_t)s * Bsz + b0 + m2) * H + j0);
  }
  __syncthreads();
  uint2 pre = {0, 0};
  if (gw) {  // W2: xg(0), xg(1) + prefetch h0(2)
    if (ldr) pre = *(const uint2*)(hsrc + ((size_t)2 * Bsz + b0 + pm) * H + pj);
#pragma unroll
    for (int s = 0; s < 2; ++s) {
      f32x4 acc[3];
#pragma unroll
      for (int i = 0; i < 3; ++i) {
        acc[i] = (f32x4){0.f, 0.f, 0.f, 0.f};
        if (!xtv[i]) continue;
#pragma unroll
        for (int kt = 0; kt < 7; ++kt) {
          bf16x8 hf = *(const bf16x8*)B2_s[s][kt * 4 + q][l16];
          acc[i] = __builtin_amdgcn_mfma_f32_16x16x32_bf16(wx[i][kt], hf, acc[i], 0, 0, 0);
        }
      }
#pragma unroll
      for (int i = 0; i < 3; ++i) {
        if (xtv[i] && l16 < 4)
          *(f32x4*)&xgr[((s * 4 + l16) * 100 + xti[i] * 4 + q) * 4] = acc[i];
      }
    }
  }
  __syncthreads();
  if (ldr) *(uint2*)&B2_s[0][dstk >> 3][pm][dstk & 7] = pre;  // W3: h0(2)->B2[0]
  __syncthreads();

  // ---------- main loop ----------
  int p = 0, s0 = 0, s2 = 2;  // s0 = t%3 (consume), s2 = (t+2)%3 (produce)
  for (int t = 0; t < Tt; ++t) {
    if (busy) {
      // gates = W_hh @ h1 (MFMA) spread + xg from ring
      f32x4 xgv = *(const f32x4*)&xgr[((s0 * 4 + m) * 100 + jme) * 4];
      bf16x8 hfrag[4];
#pragma unroll
      for (int kt = 0; kt < 4; ++kt) hfrag[kt] = *(const bf16x8*)A_s[p][kt * 4 + q][l16];
      f32x4 acc[4];
#pragma unroll
      for (int i = 0; i < 4; ++i) {
        acc[i] = (f32x4){0.f, 0.f, 0.f, 0.f};
        if (!tv[i]) continue;
#pragma unroll
        for (int kt = 0; kt < 4; ++kt)
          acc[i] = __builtin_amdgcn_mfma_f32_16x16x32_bf16(wf[i][kt], hfrag[kt], acc[i], 0, 0, 0);
      }
      float gr[4];
#pragma unroll
      for (int r = 0; r < 4; ++r) {
        float v0 = partner4(acc[0][r]);
        float v1 = partner4(acc[1][r]);
        float v2 = partner4(acc[2][r]);
        float v3 = partner4(acc[3][r]);
        float lo = (g16 & 1) ? v1 : v0;
        float hi = (g16 & 1) ? v3 : v2;
        gr[r] = ((g16 & 2) ? hi : lo) + xgv[r];
      }
      float cc = sigm(gr[1]) * c + sigm(gr[0]) * tanhf_(gr[2]);
      c = cc;
      float h = sigm(gr[3]) * tanhf_(cc);
      if (evalid) {
        A_s[1 - p][jme >> 3][m][jme & 7] = (short)f2bf(h);
        if (t == Tt - 1) hf_s[m][jme] = h;
      }
    } else {
      // producers: prefetch h0(t+3); xg(t+2) from B2[t&1]; stage -> B2[1-(t&1)]
      const bool do_pf = (t < Tt - 3);
      if (do_pf && ldr) { pre = *(const uint2*)ph; ph += Bsz * H; }
      if (t < Tt - 2) {
        f32x4 acc[3];
#pragma unroll
        for (int i = 0; i < 3; ++i) {
          acc[i] = (f32x4){0.f, 0.f, 0.f, 0.f};
          if (!xtv[i]) continue;
#pragma unroll
          for (int kt = 0; kt < 7; ++kt) {
            bf16x8 hf = *(const bf16x8*)B2_s[t & 1][kt * 4 + q][l16];
            acc[i] = __builtin_amdgcn_mfma_f32_16x16x32_bf16(wx[i][kt], hf, acc[i], 0, 0, 0);
          }
        }
#pragma unroll
        for (int i = 0; i < 3; ++i) {
          if (xtv[i] && l16 < 4)
            *(f32x4*)&xgr[((s2 * 4 + l16) * 100 + xti[i] * 4 + q) * 4] = acc[i];
        }
      }
      if (do_pf && ldr)
        *(uint2*)&B2_s[1 - (t & 1)][dstk >> 3][pm][dstk & 7] = pre;
    }
    __syncthreads();
    p ^= 1;
    s0 = (s0 == 2) ? 0 : s0 + 1;
    s2 = (s2 == 2) ? 0 : s2 + 1;
  }

  // ---- layer-1 backward single step at t=T-1 (h=c=0) ----
  {
    const size_t base = ((size_t)(Tt - 1) * Bsz + b0) * H;
    if (tid < 100) {
      int m2 = tid / 25, j0 = (tid - (tid / 25) * 25) * 4;
      *(uint2*)&A2_s[j0 >> 3][m2][j0 & 7] = *(const uint2*)(h0fT + base + m2 * H + j0);
      int k = 100 + j0;
      *(uint2*)&A2_s[k >> 3][m2][k & 7] = *(const uint2*)(h0bT + base + m2 * H + j0);
    }
  }
  __syncthreads();
  if (busy) {
    f32x4 acc[4];
#pragma unroll
    for (int i = 0; i < 4; ++i) acc[i] = (f32x4){0.f, 0.f, 0.f, 0.f};
#pragma unroll
    for (int kt = 0; kt < 7; ++kt) {
      bf16x8 hf = *(const bf16x8*)A2_s[kt * 4 + q][l16];
#pragma unroll
      for (int i = 0; i < 4; ++i) {
        if (!tv[i]) continue;
        bf16x8 wfb = *(const bf16x8*)(pk1b + ((size_t)(kt * 4 + q) * NP + mts[i] * 16 + l16) * 8);
        acc[i] = __builtin_amdgcn_mfma_f32_16x16x32_bf16(wfb, hf, acc[i], 0, 0, 0);
      }
    }
    float gr[4];
#pragma unroll
    for (int r = 0; r < 4; ++r) {
      float v0 = partner4(acc[0][r]);
      float v1 = partner4(acc[1][r]);
      float v2 = partner4(acc[2][r]);
      float v3 = partner4(acc[3][r]);
      float lo = (g16 & 1) ? v1 : v0;
      float hi = (g16 & 1) ? v3 : v2;
      gr[r] = (g16 & 2) ? hi : lo;
    }
    float cc = sigm(gr[0]) * tanhf_(gr[2]);   // c_prev = 0
    if (evalid) hb_s[m][jme] = sigm(gr[3]) * tanhf_(cc);
  }
  __syncthreads();

  // ---- FC (3x200) + softmax ----
  if (tid < MB1 * 3) {
    int mr = tid / 3, cls = tid - mr * 3;
    float s = fcb_s[cls];
    for (int jj = 0; jj < H; ++jj) s += fcw_s[cls * D1 + jj] * hf_s[mr][jj];
    for (int jj = 0; jj < H; ++jj) s += fcw_s[cls * D1 + H + jj] * hb_s[mr][jj];
    logit_s[mr][cls] = s;
  }
  __syncthreads();
  if (tid < MB1) {
    float a = logit_s[tid][0], b = logit_s[tid][1], cc = logit_s[tid][2];
    float mx = fmaxf(a, fmaxf(b, cc));
    float e0 = __expf(a - mx), e1 = __expf(b - mx), e2 = __expf(cc - mx);
    float inv = 1.f / (e0 + e1 + e2);
    out[(b0 + tid) * 3 + 0] = e0 * inv;
    out[(b0 + tid) * 3 + 1] = e1 * inv;
    out[(b0 + tid) * 3 + 2] = e2 * inv;
  }
}

extern "C" void kernel_launch(void* const* d_in, const int* in_sizes, int n_in,
                              void* d_out, int out_size, void* d_ws, size_t ws_size,
                              hipStream_t stream) {
  const float* x        = (const float*)d_in[0];
  const float* w_ih_l0f = (const float*)d_in[1];
  const float* w_hh_l0f = (const float*)d_in[2];
  const float* b_ih_l0f = (const float*)d_in[3];
  const float* b_hh_l0f = (const float*)d_in[4];
  const float* w_ih_l0b = (const float*)d_in[5];
  const float* w_hh_l0b = (const float*)d_in[6];
  const float* b_ih_l0b = (const float*)d_in[7];
  const float* b_hh_l0b = (const float*)d_in[8];
  const float* w_ih_l1f = (const float*)d_in[9];
  const float* w_hh_l1f = (const float*)d_in[10];
  const float* b_ih_l1f = (const float*)d_in[11];
  const float* b_hh_l1f = (const float*)d_in[12];
  const float* w_ih_l1b = (const float*)d_in[13];
  // d_in[14] = w_hh_l1b unused (reverse dir at t=T-1 has h=0)
  const float* b_ih_l1b = (const float*)d_in[15];
  const float* b_hh_l1b = (const float*)d_in[16];
  const float* fc_w     = (const float*)d_in[17];
  const float* fc_b     = (const float*)d_in[18];

  unsigned short* h0fT = (unsigned short*)d_ws;
  unsigned short* h0bT = h0fT + (size_t)Tt * Bsz * H;
  unsigned short* pk0f = h0bT + (size_t)Tt * Bsz * H;
  unsigned short* pk0b = pk0f + 16 * NP * 8;
  unsigned short* pkhh = pk0b + 16 * NP * 8;
  unsigned short* pkxg = pkhh + 16 * NP * 8;
  unsigned short* pk1b = pkxg + 28 * NP * 8;

  pack_all<<<dim3(448, 5), 256, 0, stream>>>(
      w_hh_l0f, w_ih_l0f, b_ih_l0f, b_hh_l0f,
      w_hh_l0b, w_ih_l0b, b_ih_l0b, b_hh_l0b,
      w_hh_l1f, b_ih_l1f, b_hh_l1f,
      w_ih_l1f, w_ih_l1b, b_ih_l1b, b_hh_l1b,
      pk0f, pk0b, pkhh, pkxg, pk1b);

  lstm_l0<<<dim3(Bsz / MB, 2), 1024, 0, stream>>>(x, pk0f, pk0b, h0fT, h0bT);
  lstm_l1<<<Bsz / MB1, 1024, 0, stream>>>(h0fT, h0bT, pkhh, pkxg, pk1b,
                                          fc_w, fc_b, (float*)d_out);
}

// Round 16
// 364.828 us; speedup vs baseline: 2.4030x; 2.4030x over previous
//
#include <hip/hip_runtime.h>
#include <hip/hip_fp16.h>

// LSTM_48850958024796 — R16: revert to R14 (measured best, 387.7 µs).
// R15's producer-consumer fusion spilled the unioned per-role register state
// (VGPR=64 allocated vs ~150 needed) -> 2.1GB scratch traffic -> 877 µs.
// Falsified levers (do not retry): barrier_nv (2x neutral), unroll-2
// (negative), mega-kernel+grid.sync (HBM round-trips, 724), wave
// specialization in one kernel (register spill, 877).
// Scan math (R3-proven): gates^T = W(A) @ [h|x|1]^T(B), cols gate-interleaved
// (n'=4j+gate). l0: MB=8, 2 tiles/wave, spread via ds_swizzle(0x17).
// l1: MB1=4, 256 blocks, dense 4 tiles/wave (waves 0..6), ds_swizzle(0x13).

typedef __attribute__((ext_vector_type(8))) short bf16x8;
typedef __attribute__((ext_vector_type(4))) float f32x4;

constexpr int Bsz = 1024, Tt = 128, IN_ = 5, H = 100, G = 400, D1 = 200;
constexpr int NP = 512;   // packed gate cols (32 tiles of 16)
constexpr int NT = 25;    // real tiles (400/16)
constexpr int MB = 8;     // batch rows per block (l0)
constexpr int MB1 = 4;    // batch rows per block (l1)

__device__ __forceinline__ float sigm(float x)   { return 1.f / (1.f + __expf(-x)); }
__device__ __forceinline__ float tanhf_(float x) { return 1.f - 2.f / (__expf(2.f * x) + 1.f); }
__device__ __forceinline__ unsigned short f2bf(float f) {
  unsigned u = __float_as_uint(f);
  u += 0x7fff + ((u >> 16) & 1);
  return (unsigned short)(u >> 16);
}
// src lane = lane & ~8 (keeps bits 0,1,2,4): MB=8 2-way spread
__device__ __forceinline__ float partner8(float v) {
  return __uint_as_float(
      (unsigned)__builtin_amdgcn_ds_swizzle((int)__float_as_uint(v), 0x17));
}
// src lane = lane & ~12 (keeps bits 0,1 and 4): MB1=4 4-way spread
__device__ __forceinline__ float partner4(float v) {
  return __uint_as_float(
      (unsigned)__builtin_amdgcn_ds_swizzle((int)__float_as_uint(v), 0x13));
}

// packed col n' (0..511): j=n'>>2, gate=n'&3, src row n = gate*100+j; j>=100->0
__device__ __forceinline__ void pack_body(
    const float* wA, int KA, const float* wB, int KB, int kbo,
    const float* b1, const float* b2, int bias_k,
    unsigned short* dst, int Kg, int idx) {
  if (idx >= Kg * NP * 8) return;
  int jj = idx & 7, rest = idx >> 3;
  int np_ = rest % NP, g = rest / NP;
  int j = np_ >> 2, gate = np_ & 3;
  int k = g * 8 + jj;
  float v = 0.f;
  if (j < H) {
    int n = gate * H + j;
    if (k < KA) v = wA[n * KA + k];
    else if (KB > 0 && k >= kbo && k < kbo + KB) v = wB[n * KB + (k - kbo)];
    else if (k == bias_k) v = b1[n] + b2[n];
  }
  dst[idx] = f2bf(v);
}

__global__ void pack_all(
    const float* __restrict__ w_hh_l0f, const float* __restrict__ w_ih_l0f,
    const float* __restrict__ b_ih_l0f, const float* __restrict__ b_hh_l0f,
    const float* __restrict__ w_hh_l0b, const float* __restrict__ w_ih_l0b,
    const float* __restrict__ b_ih_l0b, const float* __restrict__ b_hh_l0b,
    const float* __restrict__ w_hh_l1f, const float* __restrict__ b_ih_l1f,
    const float* __restrict__ b_hh_l1f,
    const float* __restrict__ w_ih_l1f, const float* __restrict__ w_ih_l1b,
    const float* __restrict__ b_ih_l1b, const float* __restrict__ b_hh_l1b,
    unsigned short* __restrict__ pk0f, unsigned short* __restrict__ pk0b,
    unsigned short* __restrict__ pkhh, unsigned short* __restrict__ pkxg,
    unsigned short* __restrict__ pk1b) {
  int idx = blockIdx.x * 256 + threadIdx.x;
  switch (blockIdx.y) {
    case 0: pack_body(w_hh_l0f, 100, w_ih_l0f, 5, 100, b_ih_l0f, b_hh_l0f, 105, pk0f, 16, idx); break;
    case 1: pack_body(w_hh_l0b, 100, w_ih_l0b, 5, 100, b_ih_l0b, b_hh_l0b, 105, pk0b, 16, idx); break;
    case 2: pack_body(w_hh_l1f, 100, nullptr, 0, 0, b_ih_l1f, b_hh_l1f, -1, pkhh, 16, idx); break;
    case 3: pack_body(w_ih_l1f, 200, nullptr, 0, 0, b_ih_l1f, b_hh_l1f, 200, pkxg, 28, idx); break;
    default: pack_body(w_ih_l1b, 200, nullptr, 0, 0, b_ih_l1b, b_hh_l1b, 200, pk1b, 28, idx);
  }
}

// ------------- layer 0 scan (grid = 128 x 2 dirs, 1024 thr) -----------------
__global__ __launch_bounds__(1024, 1) void lstm_l0(
    const float* __restrict__ x,
    const unsigned short* __restrict__ pk_f, const unsigned short* __restrict__ pk_b,
    unsigned short* __restrict__ h0fT, unsigned short* __restrict__ h0bT) {
  __shared__ __align__(16) short A_s[2][16][16][8];  // [buf][kg][m16][jj], K=128

  const int tid = threadIdx.x;
  const int lane = tid & 63, w = tid >> 6;       // 16 waves
  const int q = lane >> 4, l16 = lane & 15;
  const int b0 = blockIdx.x * MB;
  const int dir = blockIdx.y;
  const unsigned short* pk = dir ? pk_b : pk_f;
  unsigned short* hT = dir ? h0bT : h0fT;

  for (int i = tid; i < 2 * 16 * 16 * 8; i += 1024) ((short*)A_s)[i] = 0;

  const int mtA = w, mtB = w + 16;
  const bool bvalid = (mtB < NT);
  bf16x8 wfA[4], wfB[4];
#pragma unroll
  for (int kt = 0; kt < 4; ++kt) {
    wfA[kt] = *(const bf16x8*)(pk + ((size_t)(kt * 4 + q) * NP + mtA * 16 + l16) * 8);
    wfB[kt] = *(const bf16x8*)(pk + ((size_t)(kt * 4 + q) * NP + mtB * 16 + l16) * 8);
  }
  float c = 0.f;
  const bool up = (l16 >= 8);
  const int mm = l16 & 7;
  const int j = (up ? mtB : mtA) * 4 + q;
  const bool valid = up ? bvalid : true;
  const int xm = tid / IN_, xe = tid - xm * IN_;              // x loader (tid<40)
  const int sm = tid / 25, sj = (tid - (tid / 25) * 25) * 4;  // h store (tid<200)
  const float* xp = x + ((size_t)(b0 + xm) * Tt + (dir ? Tt - 2 : 1)) * IN_ + xe;
  const int xstride = dir ? -IN_ : IN_;
  unsigned short* hp =
      hT + ((size_t)(dir ? Tt - 1 : 0) * Bsz + b0 + sm) * H + sj;
  const int hstride = dir ? -(Bsz * H) : (Bsz * H);
  __syncthreads();
  if (tid < 16) {  // bias-one col k=105 (kg13,jj1), both bufs
    A_s[0][13][tid][1] = (short)f2bf(1.f);
    A_s[1][13][tid][1] = (short)f2bf(1.f);
  }
  if (tid < MB * IN_) {  // x(t_first) -> buf0, direct f32 read
    int t0 = dir ? (Tt - 1) : 0;
    int k = 100 + xe;
    A_s[0][k >> 3][xm][k & 7] =
        (short)f2bf(x[((size_t)(b0 + xm) * Tt + t0) * IN_ + xe]);
  }
  __syncthreads();

  int p = 0;
  for (int step = 0; step < Tt; ++step) {
    if (step > 0 && tid < 200) {  // coalesced store of h(prev) from buf p
      uint2 hv = *(const uint2*)&A_s[p][sj >> 3][sm][sj & 7];
      *(uint2*)hp = hv;
      hp += hstride;
    }
    float xn = 0.f;
    const bool do_x = (tid < MB * IN_) && (step < Tt - 1);
    if (do_x) { xn = *xp; xp += xstride; }
    bf16x8 hfrag[4];
#pragma unroll
    for (int kt = 0; kt < 4; ++kt) hfrag[kt] = *(const bf16x8*)A_s[p][kt * 4 + q][l16];
    f32x4 accA = (f32x4){0.f, 0.f, 0.f, 0.f};
    f32x4 accB = (f32x4){0.f, 0.f, 0.f, 0.f};
#pragma unroll
    for (int kt = 0; kt < 4; ++kt)
      accA = __builtin_amdgcn_mfma_f32_16x16x32_bf16(wfA[kt], hfrag[kt], accA, 0, 0, 0);
    if (bvalid) {
#pragma unroll
      for (int kt = 0; kt < 4; ++kt)
        accB = __builtin_amdgcn_mfma_f32_16x16x32_bf16(wfB[kt], hfrag[kt], accB, 0, 0, 0);
    }
    float pb0 = partner8(accB[0]), pb1 = partner8(accB[1]);
    float pb2 = partner8(accB[2]), pb3 = partner8(accB[3]);
    float g0 = up ? pb0 : accA[0];
    float g1 = up ? pb1 : accA[1];
    float g2 = up ? pb2 : accA[2];
    float g3 = up ? pb3 : accA[3];
    float cc = sigm(g1) * c + sigm(g0) * tanhf_(g2);
    c = cc;
    float h = sigm(g3) * tanhf_(cc);
    if (valid) A_s[1 - p][j >> 3][mm][j & 7] = (short)f2bf(h);
    if (do_x) {
      int k = 100 + xe;
      A_s[1 - p][k >> 3][xm][k & 7] = (short)f2bf(xn);
    }
    __syncthreads();
    p ^= 1;
  }
  if (tid < 200) *(uint2*)hp = *(const uint2*)&A_s[p][sj >> 3][sm][sj & 7];  // final h
}

// ---- xgT[t*1024+b][400] = [h0f|h0b] @ W_ih_l1f^T + bias (fp16, interleaved) --
__global__ __launch_bounds__(1024, 1) void gemm_xg(
    const unsigned short* __restrict__ h0fT, const unsigned short* __restrict__ h0bT,
    const unsigned short* __restrict__ pkw, __half* __restrict__ xg) {
  __shared__ __align__(16) short B_s[28][64][8];  // K=224 aug (k=200 bias-one)
  const int tid = threadIdx.x;
  const int lane = tid & 63, w = tid >> 6;   // 16 waves
  const int q = lane >> 4, l16 = lane & 15;
  const int r0 = blockIdx.x * 64;            // rows r = t*1024+b
  const size_t base = (size_t)r0 * H;

  for (int i = tid; i < 3 * 64 * 8; i += 1024) {  // kg 25..27: zero + bias-one
    int jj = i & 7, gl = i >> 9;
    ((short*)&B_s[25][0][0])[i] = (short)((gl == 0 && jj == 0) ? f2bf(1.f) : 0);
  }
  for (int idx = tid; idx < 1600; idx += 1024) {  // h0f k=0..99, h0b k=100..199
    int m = idx / 25, j0 = (idx - (idx / 25) * 25) * 4;
    *(uint2*)&B_s[j0 >> 3][m][j0 & 7] = *(const uint2*)(h0fT + base + m * H + j0);
    int k = 100 + j0;
    *(uint2*)&B_s[k >> 3][m][k & 7] = *(const uint2*)(h0bT + base + m * H + j0);
  }

  const int mtA = w, mtB = w + 16;
  const bool bvalid = (mtB < NT);
  bf16x8 wfA[7], wfB[7];
#pragma unroll
  for (int kt = 0; kt < 7; ++kt) {
    wfA[kt] = *(const bf16x8*)(pkw + ((size_t)(kt * 4 + q) * NP + mtA * 16 + l16) * 8);
    wfB[kt] = *(const bf16x8*)(pkw + ((size_t)(kt * 4 + q) * NP + mtB * 16 + l16) * 8);
  }
  const int jA = mtA * 4 + q, jB = mtB * 4 + q;
  __syncthreads();

#pragma unroll
  for (int rg = 0; rg < 4; ++rg) {
    f32x4 accA = (f32x4){0.f, 0.f, 0.f, 0.f};
    f32x4 accB = (f32x4){0.f, 0.f, 0.f, 0.f};
#pragma unroll
    for (int kt = 0; kt < 7; ++kt) {
      bf16x8 hf = *(const bf16x8*)B_s[kt * 4 + q][rg * 16 + l16];
      accA = __builtin_amdgcn_mfma_f32_16x16x32_bf16(wfA[kt], hf, accA, 0, 0, 0);
      if (bvalid)
        accB = __builtin_amdgcn_mfma_f32_16x16x32_bf16(wfB[kt], hf, accB, 0, 0, 0);
    }
    const size_t row = (size_t)(r0 + rg * 16 + l16);
    {
      __half2 h01 = __floats2half2_rn(accA[0], accA[1]);
      __half2 h23 = __floats2half2_rn(accA[2], accA[3]);
      uint2 st; *(__half2*)&st.x = h01; *(__half2*)&st.y = h23;
      *(uint2*)(xg + row * G + 4 * jA) = st;
    }
    if (bvalid) {
      __half2 h01 = __floats2half2_rn(accB[0], accB[1]);
      __half2 h23 = __floats2half2_rn(accB[2], accB[3]);
      uint2 st; *(__half2*)&st.x = h01; *(__half2*)&st.y = h23;
      *(uint2*)(xg + row * G + 4 * jB) = st;
    }
  }
}

// ---- layer 1: MB1=4, 256 blocks, dense 4 tiles/wave (waves 0..6 busy) ------
__global__ __launch_bounds__(1024, 1) void lstm_l1(
    const unsigned short* __restrict__ h0fT, const unsigned short* __restrict__ h0bT,
    const unsigned short* __restrict__ pk_hh, const unsigned short* __restrict__ pk1b,
    const __half* __restrict__ xg,
    const float* __restrict__ fc_w, const float* __restrict__ fc_b,
    float* __restrict__ out) {
  __shared__ __align__(16) short A_s[2][16][16][8];      // h1, K=128 (m 0..3 used)
  __shared__ __align__(16) short A2_s[28][16][8];        // epilogue [h0|1] K=224
  __shared__ float hf_s[MB1][H];
  __shared__ float hb_s[MB1][H];
  __shared__ float fcw_s[3 * D1];
  __shared__ float fcb_s[3];
  __shared__ float logit_s[MB1][3];

  const int tid = threadIdx.x;
  const int lane = tid & 63, w = tid >> 6;   // 16 waves
  const int q = lane >> 4, l16 = lane & 15;
  const int b0 = blockIdx.x * MB1;           // 256 blocks
  const uint2* xg2 = (const uint2*)xg;       // 100 uint2 per (t,b) row

  for (int i = tid; i < 2 * 16 * 16 * 8; i += 1024) ((short*)A_s)[i] = 0;
  for (int i = tid; i < 25 * 16 * 8; i += 1024) ((short*)A2_s)[i] = 0;  // kg 0..24
  for (int i = tid; i < 3 * 16 * 8; i += 1024) {  // A2 kg25..27 zero + bias-one
    int jj = i & 7, gl = i >> 7;
    ((short*)&A2_s[25][0][0])[i] = (short)((gl == 0 && jj == 0) ? f2bf(1.f) : 0);
  }
  for (int i = tid; i < 3 * D1; i += 1024) fcw_s[i] = fc_w[i];
  if (tid < 3) fcb_s[tid] = fc_b[tid];

  const bool busy = (w < 7);                 // waves 0..6 own tiles 4w..4w+3
  const int m = l16 & 3, g16 = l16 >> 2;
  const int myMt = w * 4 + g16;
  const int jme = myMt * 4 + q;              // my element's j (>=100 invalid)
  const bool evalid = busy && (myMt < NT);
  int mts[4]; bool tv[4];
  bf16x8 wf[4][4];
  if (busy) {
#pragma unroll
    for (int i = 0; i < 4; ++i) {
      int mt = w * 4 + i; mts[i] = mt; tv[i] = (mt < NT);
#pragma unroll
      for (int kt = 0; kt < 4; ++kt)
        wf[i][kt] = *(const bf16x8*)(pk_hh + ((size_t)(kt * 4 + q) * NP + mt * 16 + l16) * 8);
    }
  }
  float c = 0.f;
  // per-lane own-element xg, running pointer (+102400 uint2 per t);
  // invalid jme (<=111) reads <=96B past the row — lands in ws, unused.
  const uint2* xgp = xg2 + (size_t)(b0 + m) * 100 + jme;
  uint2 xgCur = {0, 0};
  if (busy) { xgCur = *xgp; xgp += Bsz * 100; }
  __syncthreads();

  int p = 0;
  for (int t = 0; t < Tt; ++t) {
    if (busy) {
      uint2 xgNxt = xgCur;
      if (t < Tt - 1) { xgNxt = *xgp; xgp += Bsz * 100; }
      bf16x8 hfrag[4];
#pragma unroll
      for (int kt = 0; kt < 4; ++kt) hfrag[kt] = *(const bf16x8*)A_s[p][kt * 4 + q][l16];
      f32x4 acc[4];
#pragma unroll
      for (int i = 0; i < 4; ++i) {
        acc[i] = (f32x4){0.f, 0.f, 0.f, 0.f};
        if (!tv[i]) continue;
#pragma unroll
        for (int kt = 0; kt < 4; ++kt)
          acc[i] = __builtin_amdgcn_mfma_f32_16x16x32_bf16(wf[i][kt], hfrag[kt], acc[i], 0, 0, 0);
      }
      // spread: all lanes swizzle unconditionally (src lane = same q, l16=m),
      // then 2-level select by g16; add own xg.
      float2 x01 = __half22float2(*(const __half2*)&xgCur.x);
      float2 x23 = __half22float2(*(const __half2*)&xgCur.y);
      float xr[4] = {x01.x, x01.y, x23.x, x23.y};
      float gr[4];
#pragma unroll
      for (int r = 0; r < 4; ++r) {
        float v0 = partner4(acc[0][r]);
        float v1 = partner4(acc[1][r]);
        float v2 = partner4(acc[2][r]);
        float v3 = partner4(acc[3][r]);
        float lo = (g16 & 1) ? v1 : v0;
        float hi = (g16 & 1) ? v3 : v2;
        gr[r] = ((g16 & 2) ? hi : lo) + xr[r];
      }
      float cc = sigm(gr[1]) * c + sigm(gr[0]) * tanhf_(gr[2]);
      c = cc;
      float h = sigm(gr[3]) * tanhf_(cc);
      if (evalid) {
        A_s[1 - p][jme >> 3][m][jme & 7] = (short)f2bf(h);
        if (t == Tt - 1) hf_s[m][jme] = h;
      }
      xgCur = xgNxt;
    }
    __syncthreads();
    p ^= 1;
  }

  // ---- layer-1 backward single step at t=T-1 (h=c=0) ----
  {
    const size_t base = ((size_t)(Tt - 1) * Bsz + b0) * H;
    if (tid < 100) {  // stage rows m=0..3 only (this block's batch)
      int m2 = tid / 25, j0 = (tid - (tid / 25) * 25) * 4;
      *(uint2*)&A2_s[j0 >> 3][m2][j0 & 7] = *(const uint2*)(h0fT + base + m2 * H + j0);
      int k = 100 + j0;
      *(uint2*)&A2_s[k >> 3][m2][k & 7] = *(const uint2*)(h0bT + base + m2 * H + j0);
    }
  }
  __syncthreads();
  if (busy) {
    f32x4 acc[4];
#pragma unroll
    for (int i = 0; i < 4; ++i) acc[i] = (f32x4){0.f, 0.f, 0.f, 0.f};
#pragma unroll
    for (int kt = 0; kt < 7; ++kt) {
      bf16x8 hf = *(const bf16x8*)A2_s[kt * 4 + q][l16];
#pragma unroll
      for (int i = 0; i < 4; ++i) {
        if (!tv[i]) continue;
        bf16x8 wfb = *(const bf16x8*)(pk1b + ((size_t)(kt * 4 + q) * NP + mts[i] * 16 + l16) * 8);
        acc[i] = __builtin_amdgcn_mfma_f32_16x16x32_bf16(wfb, hf, acc[i], 0, 0, 0);
      }
    }
    float gr[4];
#pragma unroll
    for (int r = 0; r < 4; ++r) {
      float v0 = partner4(acc[0][r]);
      float v1 = partner4(acc[1][r]);
      float v2 = partner4(acc[2][r]);
      float v3 = partner4(acc[3][r]);
      float lo = (g16 & 1) ? v1 : v0;
      float hi = (g16 & 1) ? v3 : v2;
      gr[r] = (g16 & 2) ? hi : lo;
    }
    float cc = sigm(gr[0]) * tanhf_(gr[2]);   // c_prev = 0
    if (evalid) hb_s[m][jme] = sigm(gr[3]) * tanhf_(cc);
  }
  __syncthreads();

  // ---- FC (3x200) + softmax ----
  if (tid < MB1 * 3) {
    int mr = tid / 3, cls = tid - mr * 3;
    float s = fcb_s[cls];
    for (int jj = 0; jj < H; ++jj) s += fcw_s[cls * D1 + jj] * hf_s[mr][jj];
    for (int jj = 0; jj < H; ++jj) s += fcw_s[cls * D1 + H + jj] * hb_s[mr][jj];
    logit_s[mr][cls] = s;
  }
  __syncthreads();
  if (tid < MB1) {
    float a = logit_s[tid][0], b = logit_s[tid][1], cc = logit_s[tid][2];
    float mx = fmaxf(a, fmaxf(b, cc));
    float e0 = __expf(a - mx), e1 = __expf(b - mx), e2 = __expf(cc - mx);
    float inv = 1.f / (e0 + e1 + e2);
    out[(b0 + tid) * 3 + 0] = e0 * inv;
    out[(b0 + tid) * 3 + 1] = e1 * inv;
    out[(b0 + tid) * 3 + 2] = e2 * inv;
  }
}

extern "C" void kernel_launch(void* const* d_in, const int* in_sizes, int n_in,
                              void* d_out, int out_size, void* d_ws, size_t ws_size,
                              hipStream_t stream) {
  const float* x        = (const float*)d_in[0];
  const float* w_ih_l0f = (const float*)d_in[1];
  const float* w_hh_l0f = (const float*)d_in[2];
  const float* b_ih_l0f = (const float*)d_in[3];
  const float* b_hh_l0f = (const float*)d_in[4];
  const float* w_ih_l0b = (const float*)d_in[5];
  const float* w_hh_l0b = (const float*)d_in[6];
  const float* b_ih_l0b = (const float*)d_in[7];
  const float* b_hh_l0b = (const float*)d_in[8];
  const float* w_ih_l1f = (const float*)d_in[9];
  const float* w_hh_l1f = (const float*)d_in[10];
  const float* b_ih_l1f = (const float*)d_in[11];
  const float* b_hh_l1f = (const float*)d_in[12];
  const float* w_ih_l1b = (const float*)d_in[13];
  // d_in[14] = w_hh_l1b unused (reverse dir at t=T-1 has h=0)
  const float* b_ih_l1b = (const float*)d_in[15];
  const float* b_hh_l1b = (const float*)d_in[16];
  const float* fc_w     = (const float*)d_in[17];
  const float* fc_b     = (const float*)d_in[18];

  unsigned short* h0fT = (unsigned short*)d_ws;
  unsigned short* h0bT = h0fT + (size_t)Tt * Bsz * H;
  __half* xgT          = (__half*)(h0bT + (size_t)Tt * Bsz * H);
  unsigned short* pk0f = (unsigned short*)(xgT + (size_t)Tt * Bsz * G);
  unsigned short* pk0b = pk0f + 16 * NP * 8;
  unsigned short* pkhh = pk0b + 16 * NP * 8;
  unsigned short* pkxg = pkhh + 16 * NP * 8;
  unsigned short* pk1b = pkxg + 28 * NP * 8;

  pack_all<<<dim3(448, 5), 256, 0, stream>>>(
      w_hh_l0f, w_ih_l0f, b_ih_l0f, b_hh_l0f,
      w_hh_l0b, w_ih_l0b, b_ih_l0b, b_hh_l0b,
      w_hh_l1f, b_ih_l1f, b_hh_l1f,
      w_ih_l1f, w_ih_l1b, b_ih_l1b, b_hh_l1b,
      pk0f, pk0b, pkhh, pkxg, pk1b);

  lstm_l0<<<dim3(Bsz / MB, 2), 1024, 0, stream>>>(x, pk0f, pk0b, h0fT, h0bT);
  gemm_xg<<<(Bsz * Tt) / 64, 1024, 0, stream>>>(h0fT, h0bT, pkxg, xgT);
  lstm_l1<<<Bsz / MB1, 1024, 0, stream>>>(h0fT, h0bT, pkhh, pk1b, xgT,
                                          fc_w, fc_b, (float*)d_out);
}